// Round 1
// baseline (816.329 us; speedup 1.0000x reference)
//
#include <hip/hip_runtime.h>
#include <math.h>

#define B_ 8
#define S_ 512
#define D_ 512
#define H_ 64
#define DK_ 8
#define WIDTH_ 16
#define NSEQ (S_ + 2 * WIDTH_)   // 544
#define MROWS (B_ * NSEQ)        // 4352
#define MOUT (B_ * S_)           // 4096
#define OUTHALF 4194304          // B*S*2D floats per output tensor

// ---------------- pad concat: [B,S,D] + pads -> [B,N,D] ----------------
__global__ void pad_concat(const float* __restrict__ inp,
                           const float* __restrict__ lp,
                           const float* __restrict__ rp,
                           float* __restrict__ out) {
    int idx = blockIdx.x * blockDim.x + threadIdx.x;
    int total = B_ * NSEQ * D_;
    if (idx >= total) return;
    int c = idx % D_;
    int t = idx / D_;
    int n = t % NSEQ;
    int b = t / NSEQ;
    float v;
    if (n < WIDTH_)             v = lp[n * D_ + c];
    else if (n < WIDTH_ + S_)   v = inp[((size_t)(b * S_ + (n - WIDTH_))) * D_ + c];
    else                        v = rp[(n - WIDTH_ - S_) * D_ + c];
    out[idx] = v;
}

// ---------------- tiled NT GEMM: C[m,n] = sum_k A[m,k]*B[n,k] + bias[n] ----
// M, N multiples of 64; K multiple of 16; lda/ldb/ldc multiples of 4.
#define BM 64
#define BN 64
#define BK 16

__global__ __launch_bounds__(256)
void gemm_nt(const float* __restrict__ A, int lda,
             const float* __restrict__ Bm, int ldb,
             const float* __restrict__ bias,
             float* __restrict__ C, int ldc,
             int M, int Ncols, int K) {
    __shared__ float As[BK][BM + 4];
    __shared__ float Bs[BK][BN + 4];
    const int bm = blockIdx.y * BM;
    const int bn = blockIdx.x * BN;
    const int t  = threadIdx.x;
    const int tx = t % 16;          // n direction
    const int ty = t / 16;          // m direction
    const int lrow = t / 4;         // 0..63
    const int lvec = t % 4;         // which float4 of the 16-wide k chunk

    float acc[4][4] = {};

    for (int k0 = 0; k0 < K; k0 += BK) {
        const float4 av = *(const float4*)&A[(size_t)(bm + lrow) * lda + k0 + lvec * 4];
        As[lvec * 4 + 0][lrow] = av.x;
        As[lvec * 4 + 1][lrow] = av.y;
        As[lvec * 4 + 2][lrow] = av.z;
        As[lvec * 4 + 3][lrow] = av.w;
        const float4 bv = *(const float4*)&Bm[(size_t)(bn + lrow) * ldb + k0 + lvec * 4];
        Bs[lvec * 4 + 0][lrow] = bv.x;
        Bs[lvec * 4 + 1][lrow] = bv.y;
        Bs[lvec * 4 + 2][lrow] = bv.z;
        Bs[lvec * 4 + 3][lrow] = bv.w;
        __syncthreads();
#pragma unroll
        for (int kk = 0; kk < BK; kk++) {
            const float4 a4 = *(const float4*)&As[kk][ty * 4];
            const float4 b4 = *(const float4*)&Bs[kk][tx * 4];
            const float a[4] = {a4.x, a4.y, a4.z, a4.w};
            const float b[4] = {b4.x, b4.y, b4.z, b4.w};
#pragma unroll
            for (int i = 0; i < 4; i++)
#pragma unroll
                for (int j = 0; j < 4; j++)
                    acc[i][j] = fmaf(a[i], b[j], acc[i][j]);
        }
        __syncthreads();
    }

#pragma unroll
    for (int i = 0; i < 4; i++) {
        const int row = bm + ty * 4 + i;
#pragma unroll
        for (int j = 0; j < 4; j++) {
            const int col = bn + tx * 4 + j;
            float bi = bias ? bias[col] : 0.f;
            C[(size_t)row * ldc + col] = acc[i][j] + bi;
        }
    }
}

// ---------------- windowed attention ----------------
// qkv: [B*N, 1536] (q cols 0:512, k 512:1024, v 1024:1536); out: [B*N, 512]
// window for query i: keys j in [i+dlo, i+dhi] clamped to [0, N-1]
__global__ __launch_bounds__(64)
void attn_window(const float* __restrict__ qkv,
                 float* __restrict__ out,
                 int dlo, int dhi) {
    const int h  = threadIdx.x;   // head 0..63
    const int bi = blockIdx.x;    // 0..B*N-1
    const int i  = bi % NSEQ;
    const int b  = bi / NSEQ;
    const float scale = 0.35355339059327373f;  // 1/sqrt(8)

    int j0 = i + dlo; if (j0 < 0) j0 = 0;
    int j1 = i + dhi; if (j1 > NSEQ - 1) j1 = NSEQ - 1;
    const int nw = j1 - j0 + 1;   // <= 18

    float q[DK_];
    const float* qrow = qkv + (size_t)bi * 1536 + h * DK_;
#pragma unroll
    for (int d = 0; d < DK_; d++) q[d] = qrow[d];

    float s[2 * WIDTH_ + 2];  // up to 18 live
    float mx = -1e30f;
    for (int jj = 0; jj < nw; jj++) {
        const float* krow = qkv + (size_t)(b * NSEQ + j0 + jj) * 1536 + 512 + h * DK_;
        float dot = 0.f;
#pragma unroll
        for (int d = 0; d < DK_; d++) dot = fmaf(q[d], krow[d], dot);
        dot *= scale;
        s[jj] = dot;
        mx = fmaxf(mx, dot);
    }
    float sum = 0.f;
    for (int jj = 0; jj < nw; jj++) { s[jj] = __expf(s[jj] - mx); sum += s[jj]; }
    const float inv = 1.f / sum;

    float o[DK_] = {};
    for (int jj = 0; jj < nw; jj++) {
        const float* vrow = qkv + (size_t)(b * NSEQ + j0 + jj) * 1536 + 1024 + h * DK_;
        const float p = s[jj] * inv;
#pragma unroll
        for (int d = 0; d < DK_; d++) o[d] = fmaf(p, vrow[d], o[d]);
    }
    float* orow = out + (size_t)bi * 512 + h * DK_;
#pragma unroll
    for (int d = 0; d < DK_; d++) orow[d] = o[d];
}

// ---------------- slice [B, WIDTH:WIDTH+S, D] -> dst (ld=1024) ----------------
__global__ void slice_to_out(const float* __restrict__ src,  // [B*N, 512]
                             float* __restrict__ dst) {      // [B*S, ld 1024], col base applied
    int idx = blockIdx.x * blockDim.x + threadIdx.x;
    int total = B_ * S_ * D_;
    if (idx >= total) return;
    int c = idx % D_;
    int m = idx / D_;
    int sidx = m % S_;
    int b = m / S_;
    dst[(size_t)m * 1024 + c] = src[((size_t)(b * NSEQ + WIDTH_ + sidx)) * 512 + c];
}

// ---------------- highway gate combine (in place on x, ld=1024) ------------
__global__ void hw_combine(float* __restrict__ x,            // col base applied
                           const float* __restrict__ proj) { // [4096, 1024]
    int idx = blockIdx.x * blockDim.x + threadIdx.x;
    int total = MOUT * D_;
    if (idx >= total) return;
    int c = idx % D_;
    int m = idx / D_;
    float nl = proj[(size_t)m * 1024 + c];
    float g  = proj[(size_t)m * 1024 + 512 + c];
    g = 1.f / (1.f + __expf(-g));
    nl = fmaxf(nl, 0.f);
    float xv = x[(size_t)m * 1024 + c];
    x[(size_t)m * 1024 + c] = g * xv + (1.f - g) * nl;
}

// ---------------- duplicate last -> all_layers ----------------
__global__ void copy4(const float* __restrict__ src, float* __restrict__ dst, int n4) {
    int idx = blockIdx.x * blockDim.x + threadIdx.x;
    if (idx >= n4) return;
    ((float4*)dst)[idx] = ((const float4*)src)[idx];
}

extern "C" void kernel_launch(void* const* d_in, const int* in_sizes, int n_in,
                              void* d_out, int out_size, void* d_ws, size_t ws_size,
                              hipStream_t stream) {
    const float* inputs    = (const float*)d_in[0];
    const float* left_pad  = (const float*)d_in[1];
    const float* right_pad = (const float*)d_in[2];
    const float* l_Wqkv = (const float*)d_in[3];
    const float* l_bqkv = (const float*)d_in[4];
    const float* l_Wo   = (const float*)d_in[5];
    const float* l_bo   = (const float*)d_in[6];
    const float* r_Wqkv = (const float*)d_in[7];
    const float* r_bqkv = (const float*)d_in[8];
    const float* r_Wo   = (const float*)d_in[9];
    const float* r_bo   = (const float*)d_in[10];
    const float* lhw_W  = (const float*)d_in[11];
    const float* lhw_b  = (const float*)d_in[12];
    const float* rhw_W  = (const float*)d_in[13];
    const float* rhw_b  = (const float*)d_in[14];

    float* out  = (float*)d_out;
    float* ws   = (float*)d_ws;
    float* padX = ws;                       // 2,228,224 floats
    float* qkvb = ws + 2228224;             // 6,684,672
    float* att  = ws + 8912896;             // 2,228,224
    float* attp = ws + 11141120;            // 2,228,224
    float* hwp  = ws + 13369344;            // 4,194,304
    float* out_all  = out;                  // all_layers [1,B,S,2D]
    float* out_last = out + OUTHALF;        // last       [B,S,2D]

    // 1. build padded input
    {
        int total = B_ * NSEQ * D_;
        pad_concat<<<(total + 255) / 256, 256, 0, stream>>>(inputs, left_pad, right_pad, padX);
    }

    for (int dir = 0; dir < 2; dir++) {
        const float* Wqkv = dir ? r_Wqkv : l_Wqkv;
        const float* bqkv = dir ? r_bqkv : l_bqkv;
        const float* Wo   = dir ? r_Wo   : l_Wo;
        const float* bo   = dir ? r_bo   : l_bo;
        const float* hwW  = dir ? rhw_W  : lhw_W;
        const float* hwb  = dir ? rhw_b  : lhw_b;
        float* xcol = out_last + (dir ? 512 : 0);   // x buffer, ld=1024

        // QKV projection: [4352,512] x [1536,512]^T -> [4352,1536]
        {
            dim3 g(1536 / BN, MROWS / BM);
            gemm_nt<<<g, 256, 0, stream>>>(padX, 512, Wqkv, 512, bqkv, qkvb, 1536,
                                           MROWS, 1536, 512);
        }
        // windowed attention
        attn_window<<<MROWS, 64, 0, stream>>>(qkvb, att,
                                              dir ? 0 : -(WIDTH_ + 1),
                                              dir ? (WIDTH_ + 1) : 0);
        // output projection: [4352,512] x [512,512]^T -> [4352,512]
        {
            dim3 g(512 / BN, MROWS / BM);
            gemm_nt<<<g, 256, 0, stream>>>(att, 512, Wo, 512, bo, attp, 512,
                                           MROWS, 512, 512);
        }
        // slice into output buffer (x for highway)
        {
            int total = B_ * S_ * D_;
            slice_to_out<<<(total + 255) / 256, 256, 0, stream>>>(attp, xcol);
        }
        // highway layers
        for (int l = 0; l < 2; l++) {
            const float* W = hwW + (size_t)l * 1024 * 512;
            const float* bb = hwb + (size_t)l * 1024;
            dim3 g(1024 / BN, MOUT / BM);
            gemm_nt<<<g, 256, 0, stream>>>(xcol, 1024, W, 512, bb, hwp, 1024,
                                           MOUT, 1024, 512);
            int total = MOUT * D_;
            hw_combine<<<(total + 255) / 256, 256, 0, stream>>>(xcol, hwp);
        }
    }

    // all_layers = last[None]
    copy4<<<(OUTHALF / 4 + 255) / 256, 256, 0, stream>>>(out_last, out_all, OUTHALF / 4);
}

// Round 2
// 333.646 us; speedup vs baseline: 2.4467x; 2.4467x over previous
//
#include <hip/hip_runtime.h>
#include <math.h>

#define B_ 8
#define S_ 512
#define D_ 512
#define WIDTH_ 16
#define NSEQ 544                 // S + 2*WIDTH
#define MROWS 4352               // B*NSEQ
#define MOUT 4096                // B*S
#define OUTHALF 4194304          // B*S*2D floats per output tensor

typedef _Float16 half8 __attribute__((ext_vector_type(8)));
typedef _Float16 half4 __attribute__((ext_vector_type(4)));
typedef float floatx4 __attribute__((ext_vector_type(4)));

// async global->LDS, 16B per lane, dest = wave-uniform base + lane*16
#define GLD16(g, l) __builtin_amdgcn_global_load_lds(                          \
    (const __attribute__((address_space(1))) void*)(g),                        \
    (__attribute__((address_space(3))) void*)(l), 16, 0, 0)

// ---------------- f16 MFMA NT GEMM (m97 structure) ----------------
// C[m,n] = sum_k A[m,k]*B[n,k] + bias[n].  A:[M,K] f16 ld=lda, B:[N,K] f16
// ld=ldb, C f32 ld=ldc.  M%128==0, N%128==0, K%32==0.
// grid = (N/128, M/128), block = 256 (4 waves, 2x2 of 64x64).
__global__ __launch_bounds__(256)
void gemm16_nt(const _Float16* __restrict__ A, int lda,
               const _Float16* __restrict__ B, int ldb,
               const float* __restrict__ bias,
               float* __restrict__ C, int ldc, int K) {
    __shared__ _Float16 As[128 * 32];   // 8 KB, row-major rows of 32 f16 (64B)
    __shared__ _Float16 Bs[128 * 32];
    const int t    = threadIdx.x;
    const int wave = t >> 6;
    const int lane = t & 63;
    const int bm = blockIdx.y * 128;
    const int bn = blockIdx.x * 128;
    const int wm = (wave & 1) * 64;     // wave's 64x64 sub-tile
    const int wn = (wave >> 1) * 64;

    // staging: 8 x (1KB global_load_lds) per tile; wave w issues insts 2w,2w+1
    const int inst = wave * 2;
    const int r0 = inst * 16 + (lane >> 2);   // row covered by this lane
    const int kf = (lane & 3) * 8;            // f16 offset within 32-wide k row

    const _Float16* Ag0 = A + (size_t)(bm + r0) * lda + kf;
    const _Float16* Ag1 = Ag0 + (size_t)16 * lda;
    const _Float16* Bg0 = B + (size_t)(bn + r0) * ldb + kf;
    const _Float16* Bg1 = Bg0 + (size_t)16 * ldb;
    _Float16* As0 = &As[inst * 512];          // wave-uniform LDS bases
    _Float16* As1 = As0 + 512;
    _Float16* Bs0 = &Bs[inst * 512];
    _Float16* Bs1 = Bs0 + 512;

    const int fr = lane & 15;                 // fragment row (m / n)
    const int fq = (lane >> 4) * 8;           // fragment k offset

    floatx4 acc[4][4] = {};

    for (int k0 = 0; k0 < K; k0 += 32) {
        GLD16(Ag0, As0);
        GLD16(Ag1, As1);
        GLD16(Bg0, Bs0);
        GLD16(Bg1, Bs1);
        Ag0 += 32; Ag1 += 32; Bg0 += 32; Bg1 += 32;
        __syncthreads();                      // drains vmcnt (m97 pattern)
        half8 af[4], bf[4];
#pragma unroll
        for (int s = 0; s < 4; s++) {
            af[s] = *(const half8*)&As[(wm + s * 16 + fr) * 32 + fq];
            bf[s] = *(const half8*)&Bs[(wn + s * 16 + fr) * 32 + fq];
        }
#pragma unroll
        for (int i = 0; i < 4; i++)
#pragma unroll
            for (int j = 0; j < 4; j++)
                acc[i][j] = __builtin_amdgcn_mfma_f32_16x16x32_f16(
                    af[i], bf[j], acc[i][j], 0, 0, 0);
        __syncthreads();
    }

    // C/D layout (verified m89/m91): col = lane&15, row = (lane>>4)*4 + reg
    const int rq = (lane >> 4) * 4;
    const int cc = lane & 15;
#pragma unroll
    for (int i = 0; i < 4; i++) {
        const int rbase = bm + wm + i * 16 + rq;
#pragma unroll
        for (int j = 0; j < 4; j++) {
            const int col = bn + wn + j * 16 + cc;
            const float bv = bias[col];
#pragma unroll
            for (int r = 0; r < 4; r++)
                C[(size_t)(rbase + r) * ldc + col] = acc[i][j][r] + bv;
        }
    }
}

// ---------------- windowed attention ----------------
// qkv f32 [MROWS,1536] (q|k|v each 512); att f16 [MROWS,512].
// One wave = one (b,i) across all 64 heads -> window bounds wave-uniform.
// window: j in [i+dlo, i+dlo+17] intersect [0, NSEQ-1].
__global__ __launch_bounds__(256)
void attn_win(const float* __restrict__ qkv, _Float16* __restrict__ att, int dlo) {
    const int tid = blockIdx.x * 256 + threadIdx.x;
    const int h  = tid & 63;
    const int bi = tid >> 6;
    const int i  = bi % NSEQ;
    const int b  = bi / NSEQ;
    const int j0 = i + dlo;
    const float scale = 0.35355339059327373f;  // 1/sqrt(8)

    const float* qr = qkv + (size_t)bi * 1536 + h * 8;
    const float4 q0 = *(const float4*)qr;
    const float4 q1 = *(const float4*)(qr + 4);

    float s[18];
    float mx = -1e30f;
#pragma unroll
    for (int jj = 0; jj < 18; jj++) {
        const int j = j0 + jj;
        const int jc = j < 0 ? 0 : (j > NSEQ - 1 ? NSEQ - 1 : j);
        const float* kr = qkv + (size_t)(b * NSEQ + jc) * 1536 + 512 + h * 8;
        const float4 k0 = *(const float4*)kr;
        const float4 k1 = *(const float4*)(kr + 4);
        float d = q0.x * k0.x + q0.y * k0.y + q0.z * k0.z + q0.w * k0.w
                + q1.x * k1.x + q1.y * k1.y + q1.z * k1.z + q1.w * k1.w;
        s[jj] = (j == jc) ? d * scale : -1e30f;
        mx = fmaxf(mx, s[jj]);
    }
    float sum = 0.f;
#pragma unroll
    for (int jj = 0; jj < 18; jj++) { s[jj] = __expf(s[jj] - mx); sum += s[jj]; }
    const float inv = 1.f / sum;

    float o[8] = {};
#pragma unroll
    for (int jj = 0; jj < 18; jj++) {
        const int j = j0 + jj;
        const int jc = j < 0 ? 0 : (j > NSEQ - 1 ? NSEQ - 1 : j);
        const float* vr = qkv + (size_t)(b * NSEQ + jc) * 1536 + 1024 + h * 8;
        const float4 v0 = *(const float4*)vr;
        const float4 v1 = *(const float4*)(vr + 4);
        const float p = s[jj];
        o[0] += p * v0.x; o[1] += p * v0.y; o[2] += p * v0.z; o[3] += p * v0.w;
        o[4] += p * v1.x; o[5] += p * v1.y; o[6] += p * v1.z; o[7] += p * v1.w;
    }
    half8 o16;
#pragma unroll
    for (int d = 0; d < 8; d++) o16[d] = (_Float16)(o[d] * inv);
    *(half8*)&att[(size_t)bi * 512 + h * 8] = o16;
}

// ---------------- f32 -> f16 convert (weights) ----------------
__global__ void cvt16(const float* __restrict__ src, _Float16* __restrict__ dst, int n4) {
    int idx = blockIdx.x * blockDim.x + threadIdx.x;
    if (idx >= n4) return;
    const float4 v = ((const float4*)src)[idx];
    half4 h = { (_Float16)v.x, (_Float16)v.y, (_Float16)v.z, (_Float16)v.w };
    ((half4*)dst)[idx] = h;
}

// ---------------- pad concat -> f16 [MROWS,512] ----------------
__global__ void pad_concat16(const float* __restrict__ inp,
                             const float* __restrict__ lp,
                             const float* __restrict__ rp,
                             _Float16* __restrict__ out) {
    int idx = blockIdx.x * blockDim.x + threadIdx.x;   // MROWS*128
    if (idx >= MROWS * 128) return;
    const int c4 = idx & 127;
    const int t  = idx >> 7;
    const int n = t % NSEQ;
    const int b = t / NSEQ;
    const float* src;
    if (n < WIDTH_)            src = lp + n * 512;
    else if (n < WIDTH_ + S_)  src = inp + ((size_t)(b * S_ + n - WIDTH_)) * 512;
    else                       src = rp + (n - WIDTH_ - S_) * 512;
    const float4 v = *(const float4*)(src + c4 * 4);
    half4 h = { (_Float16)v.x, (_Float16)v.y, (_Float16)v.z, (_Float16)v.w };
    *(half4*)&out[(size_t)t * 512 + c4 * 4] = h;
}

// ------- slice rows [WIDTH:WIDTH+S] -> xcol f32 (ld 1024) + x16 f16 -------
__global__ void slice_x(const float* __restrict__ attp,
                        float* __restrict__ xcol, _Float16* __restrict__ x16) {
    int idx = blockIdx.x * blockDim.x + threadIdx.x;   // MOUT*128
    if (idx >= MOUT * 128) return;
    const int c4 = idx & 127;
    const int m  = idx >> 7;
    const int si = m % S_;
    const int b  = m / S_;
    const float4 v = *(const float4*)&attp[((size_t)(b * NSEQ + WIDTH_ + si)) * 512 + c4 * 4];
    *(float4*)&xcol[(size_t)m * 1024 + c4 * 4] = v;
    half4 h = { (_Float16)v.x, (_Float16)v.y, (_Float16)v.z, (_Float16)v.w };
    *(half4*)&x16[(size_t)m * 512 + c4 * 4] = h;
}

// ------- highway combine: x = g*x + (1-g)*relu(nl); also emit f16 copy ----
__global__ void hw_combine(float* __restrict__ x, const float* __restrict__ proj,
                           _Float16* __restrict__ x16) {
    int idx = blockIdx.x * blockDim.x + threadIdx.x;   // MOUT*128
    if (idx >= MOUT * 128) return;
    const int c4 = idx & 127;
    const int m  = idx >> 7;
    const float4 nl = *(const float4*)&proj[(size_t)m * 1024 + c4 * 4];
    const float4 gt = *(const float4*)&proj[(size_t)m * 1024 + 512 + c4 * 4];
    float4 xv = *(float4*)&x[(size_t)m * 1024 + c4 * 4];
    float r[4];
    const float n[4] = {nl.x, nl.y, nl.z, nl.w};
    const float g[4] = {gt.x, gt.y, gt.z, gt.w};
    const float xo[4] = {xv.x, xv.y, xv.z, xv.w};
#pragma unroll
    for (int c = 0; c < 4; c++) {
        const float gg = 1.f / (1.f + __expf(-g[c]));
        r[c] = gg * xo[c] + (1.f - gg) * fmaxf(n[c], 0.f);
    }
    float4 rv = {r[0], r[1], r[2], r[3]};
    *(float4*)&x[(size_t)m * 1024 + c4 * 4] = rv;
    half4 h = { (_Float16)r[0], (_Float16)r[1], (_Float16)r[2], (_Float16)r[3] };
    *(half4*)&x16[(size_t)m * 512 + c4 * 4] = h;
}

// ---------------- duplicate last -> all_layers ----------------
__global__ void copy4(const float* __restrict__ src, float* __restrict__ dst, int n4) {
    int idx = blockIdx.x * blockDim.x + threadIdx.x;
    if (idx >= n4) return;
    ((float4*)dst)[idx] = ((const float4*)src)[idx];
}

extern "C" void kernel_launch(void* const* d_in, const int* in_sizes, int n_in,
                              void* d_out, int out_size, void* d_ws, size_t ws_size,
                              hipStream_t stream) {
    const float* inputs    = (const float*)d_in[0];
    const float* left_pad  = (const float*)d_in[1];
    const float* right_pad = (const float*)d_in[2];
    const float* l_Wqkv = (const float*)d_in[3];
    const float* l_bqkv = (const float*)d_in[4];
    const float* l_Wo   = (const float*)d_in[5];
    const float* l_bo   = (const float*)d_in[6];
    const float* r_Wqkv = (const float*)d_in[7];
    const float* r_bqkv = (const float*)d_in[8];
    const float* r_Wo   = (const float*)d_in[9];
    const float* r_bo   = (const float*)d_in[10];
    const float* lhw_W  = (const float*)d_in[11];
    const float* lhw_b  = (const float*)d_in[12];
    const float* rhw_W  = (const float*)d_in[13];
    const float* rhw_b  = (const float*)d_in[14];

    float* out = (float*)d_out;
    float* ws  = (float*)d_ws;

    // ws layout (float offsets):
    _Float16* padX16 = (_Float16*)ws;                         // 2,228,224 f16
    _Float16* w16    = (_Float16*)(ws + 1114112);             // 4,194,304 f16 arena
    _Float16* lqkv16 = w16;
    _Float16* rqkv16 = w16 + 786432;
    _Float16* lWo16  = w16 + 1572864;
    _Float16* rWo16  = w16 + 1835008;
    _Float16* lhw16  = w16 + 2097152;
    _Float16* rhw16  = w16 + 3145728;
    float* qkv  = ws + 3211264;                               // 6,684,672 f32
    float* attp = ws + 3211264;                               // alias (qkv dead)
    float* hwp  = ws + 5439488;                               // alias (qkv dead)
    _Float16* att16 = (_Float16*)(ws + 9895936);              // 2,228,224 f16
    _Float16* x16   = (_Float16*)(ws + 11010048);             // 2,097,152 f16

    float* out_all  = out;            // all_layers [1,B,S,2D]
    float* out_last = out + OUTHALF;  // last       [B,S,2D]

    // weight conversions (f32 -> f16)
    cvt16<<<768,  256, 0, stream>>>(l_Wqkv, lqkv16, 196608);
    cvt16<<<768,  256, 0, stream>>>(r_Wqkv, rqkv16, 196608);
    cvt16<<<256,  256, 0, stream>>>(l_Wo,   lWo16,   65536);
    cvt16<<<256,  256, 0, stream>>>(r_Wo,   rWo16,   65536);
    cvt16<<<1024, 256, 0, stream>>>(lhw_W,  lhw16,  262144);
    cvt16<<<1024, 256, 0, stream>>>(rhw_W,  rhw16,  262144);

    pad_concat16<<<(MROWS * 128 + 255) / 256, 256, 0, stream>>>(
        inputs, left_pad, right_pad, padX16);

    for (int dir = 0; dir < 2; dir++) {
        const _Float16* Wqkv16 = dir ? rqkv16 : lqkv16;
        const float*    bqkv   = dir ? r_bqkv : l_bqkv;
        const _Float16* Wo16   = dir ? rWo16 : lWo16;
        const float*    bo     = dir ? r_bo : l_bo;
        const _Float16* hwW16  = dir ? rhw16 : lhw16;
        const float*    hwb    = dir ? rhw_b : lhw_b;
        float* xcol = out_last + (dir ? 512 : 0);   // x buffer, ld=1024

        // QKV: [4352,512] x [1536,512]^T -> f32 [4352,1536]
        gemm16_nt<<<dim3(12, 34), 256, 0, stream>>>(
            padX16, 512, Wqkv16, 512, bqkv, qkv, 1536, 512);

        // windowed attention -> att16 f16 [4352,512]
        attn_win<<<MROWS * 64 / 256, 256, 0, stream>>>(
            qkv, att16, dir ? 0 : -(WIDTH_ + 1));

        // output projection: [4352,512] x [512,512]^T -> f32 [4352,512]
        gemm16_nt<<<dim3(4, 34), 256, 0, stream>>>(
            att16, 512, Wo16, 512, bo, attp, 512, 512);

        // slice to x (f32 in out_last cols, f16 for next GEMM)
        slice_x<<<(MOUT * 128 + 255) / 256, 256, 0, stream>>>(attp, xcol, x16);

        // highway layers
        for (int l = 0; l < 2; l++) {
            gemm16_nt<<<dim3(8, 32), 256, 0, stream>>>(
                x16, 512, hwW16 + (size_t)l * 524288, 512, hwb + (size_t)l * 1024,
                hwp, 1024, 512);
            hw_combine<<<(MOUT * 128 + 255) / 256, 256, 0, stream>>>(xcol, hwp, x16);
        }
    }

    // all_layers = last[None]
    copy4<<<(OUTHALF / 4 + 255) / 256, 256, 0, stream>>>(out_last, out_all, OUTHALF / 4);
}

// Round 4
// 229.043 us; speedup vs baseline: 3.5641x; 1.4567x over previous
//
#include <hip/hip_runtime.h>
#include <math.h>

#define B_ 8
#define S_ 512
#define D_ 512
#define WIDTH_ 16
#define NSEQ 544                 // S + 2*WIDTH
#define MROWS 4352               // B*NSEQ
#define MOUT 4096                // B*S
#define OUTHALF 4194304          // B*S*2D floats per output tensor

typedef _Float16 half8 __attribute__((ext_vector_type(8)));
typedef _Float16 half4 __attribute__((ext_vector_type(4)));
typedef float floatx4 __attribute__((ext_vector_type(4)));

// async global->LDS, 16B per lane, dest = wave-uniform base + lane*16
#define GLD16(g, l) __builtin_amdgcn_global_load_lds(                          \
    (const __attribute__((address_space(1))) void*)(g),                        \
    (__attribute__((address_space(3))) void*)(l), 16, 0, 0)

__device__ __forceinline__ float sigmoidf_(float x) {
    return 1.f / (1.f + __expf(-x));
}

// ================= QKV GEMM: 128x128 tile, f16 out, dual-dir =================
// C16[z][m,n] = sum_k A[m,k]*B[z][n,k] + bias[z][n]
// A: padX16 [4352,512] shared across z. grid (12, 34, 2), block 256.
__global__ __launch_bounds__(256)
void gemm_qkv(const _Float16* __restrict__ A,
              const _Float16* __restrict__ B0, const _Float16* __restrict__ B1,
              const float* __restrict__ bias0, const float* __restrict__ bias1,
              _Float16* __restrict__ C16) {
    const int lda = 512, ldb = 512, ldc = 1536, K = 512;
    __shared__ _Float16 As[128 * 32];
    __shared__ _Float16 Bs[128 * 32];
    const int t    = threadIdx.x;
    const int wave = t >> 6;
    const int lane = t & 63;
    const int bm = blockIdx.y * 128;
    const int bn = blockIdx.x * 128;
    const int z  = blockIdx.z;
    const _Float16* B = z ? B1 : B0;
    const float* bias = z ? bias1 : bias0;
    _Float16* C = C16 + (size_t)z * MROWS * 1536;
    const int wm = (wave & 1) * 64;
    const int wn = (wave >> 1) * 64;

    const int inst = wave * 2;
    const int r0 = inst * 16 + (lane >> 2);   // 16 rows per GLD16 inst
    const int kf = (lane & 3) * 8;

    const _Float16* Ag0 = A + (size_t)(bm + r0) * lda + kf;
    const _Float16* Ag1 = Ag0 + (size_t)16 * lda;
    const _Float16* Bg0 = B + (size_t)(bn + r0) * ldb + kf;
    const _Float16* Bg1 = Bg0 + (size_t)16 * ldb;
    _Float16* As0 = &As[inst * 512];          // 512 f16 per inst
    _Float16* As1 = As0 + 512;
    _Float16* Bs0 = &Bs[inst * 512];
    _Float16* Bs1 = Bs0 + 512;

    const int fr = lane & 15;
    const int fq = (lane >> 4) * 8;

    floatx4 acc[4][4] = {};

    for (int k0 = 0; k0 < K; k0 += 32) {
        GLD16(Ag0, As0); GLD16(Ag1, As1);
        GLD16(Bg0, Bs0); GLD16(Bg1, Bs1);
        Ag0 += 32; Ag1 += 32; Bg0 += 32; Bg1 += 32;
        __syncthreads();
        half8 af[4], bf[4];
#pragma unroll
        for (int s = 0; s < 4; s++) {
            af[s] = *(const half8*)&As[(wm + s * 16 + fr) * 32 + fq];
            bf[s] = *(const half8*)&Bs[(wn + s * 16 + fr) * 32 + fq];
        }
#pragma unroll
        for (int i = 0; i < 4; i++)
#pragma unroll
            for (int j = 0; j < 4; j++)
                acc[i][j] = __builtin_amdgcn_mfma_f32_16x16x32_f16(
                    af[i], bf[j], acc[i][j], 0, 0, 0);
        __syncthreads();
    }

    const int rq = (lane >> 4) * 4;
    const int cc = lane & 15;
#pragma unroll
    for (int i = 0; i < 4; i++) {
        const int rbase = bm + wm + i * 16 + rq;
#pragma unroll
        for (int j = 0; j < 4; j++) {
            const int col = bn + wn + j * 16 + cc;
            const float bv = bias[col];
#pragma unroll
            for (int r = 0; r < 4; r++)
                C[(size_t)(rbase + r) * ldc + col] = (_Float16)(acc[i][j][r] + bv);
        }
    }
}

// ======== Wo GEMM: 64x128 tile, dual-dir, fused slice epilogue ========
// attp[m,n] = sum_k att16[z][m,k]*Wo[z][n,k] + bo[z][n]; rows sliced
// [b,16:528] -> xcol f32 (ld 1024) + x16a f16.  grid (4, 68, 2), block 256.
__global__ __launch_bounds__(256)
void gemm_wo(const _Float16* __restrict__ Aall,
             const _Float16* __restrict__ B0, const _Float16* __restrict__ B1,
             const float* __restrict__ bias0, const float* __restrict__ bias1,
             float* __restrict__ xbase,        // out_last; +z*512, ld 1024
             _Float16* __restrict__ x16base) { // +z*MOUT*512
    const int lda = 512, ldb = 512, K = 512;
    __shared__ _Float16 As[64 * 32];    // 4 KB
    __shared__ _Float16 Bs[128 * 32];   // 8 KB
    const int t    = threadIdx.x;
    const int wave = t >> 6;
    const int lane = t & 63;
    const int bm = blockIdx.y * 64;
    const int bn = blockIdx.x * 128;
    const int z  = blockIdx.z;
    const _Float16* A = Aall + (size_t)z * MROWS * 512;
    const _Float16* B = z ? B1 : B0;
    const float* bias = z ? bias1 : bias0;
    float* xcol = xbase + z * 512;
    _Float16* x16 = x16base + (size_t)z * MOUT * 512;

    const int wm = (wave & 1) * 32;
    const int wn = (wave >> 1) * 64;

    const int rA = wave * 16 + (lane >> 2);        // A inst = wave (16 rows)
    const int rB = wave * 32 + (lane >> 2);        // B insts = 2w, 2w+1
    const int kf = (lane & 3) * 8;

    const _Float16* Ag0 = A + (size_t)(bm + rA) * lda + kf;
    const _Float16* Bg0 = B + (size_t)(bn + rB) * ldb + kf;
    const _Float16* Bg1 = Bg0 + (size_t)16 * ldb;
    _Float16* As0 = &As[wave * 512];    // FIX: 512 f16 per inst (was 256)
    _Float16* Bs0 = &Bs[wave * 1024];
    _Float16* Bs1 = Bs0 + 512;

    const int fr = lane & 15;
    const int fq = (lane >> 4) * 8;

    floatx4 acc[2][4] = {};

    for (int k0 = 0; k0 < K; k0 += 32) {
        GLD16(Ag0, As0);
        GLD16(Bg0, Bs0); GLD16(Bg1, Bs1);
        Ag0 += 32; Bg0 += 32; Bg1 += 32;
        __syncthreads();
        half8 af[2], bf[4];
#pragma unroll
        for (int s = 0; s < 2; s++)
            af[s] = *(const half8*)&As[(wm + s * 16 + fr) * 32 + fq];
#pragma unroll
        for (int s = 0; s < 4; s++)
            bf[s] = *(const half8*)&Bs[(wn + s * 16 + fr) * 32 + fq];
#pragma unroll
        for (int i = 0; i < 2; i++)
#pragma unroll
            for (int j = 0; j < 4; j++)
                acc[i][j] = __builtin_amdgcn_mfma_f32_16x16x32_f16(
                    af[i], bf[j], acc[i][j], 0, 0, 0);
        __syncthreads();
    }

    const int rq = (lane >> 4) * 4;
    const int cc = lane & 15;
#pragma unroll
    for (int i = 0; i < 2; i++) {
        const int rbase = bm + wm + i * 16 + rq;
#pragma unroll
        for (int r = 0; r < 4; r++) {
            const int row = rbase + r;
            const int b = row / NSEQ;
            const int s = row - b * NSEQ;
            if (s < WIDTH_ || s >= WIDTH_ + S_) continue;
            const int m = b * S_ + s - WIDTH_;
#pragma unroll
            for (int j = 0; j < 4; j++) {
                const int col = bn + wn + j * 16 + cc;
                const float v = acc[i][j][r] + bias[col];
                xcol[(size_t)m * 1024 + col] = v;
                x16[(size_t)m * 512 + col] = (_Float16)v;
            }
        }
    }
}

// ==== Highway GEMM: 64x128 tile, dual-N (nonlin+gate), fused combine ====
// nl = x@Wnl^T + bnl; g = sigmoid(x@Wg^T + bg); x' = g*x + (1-g)*relu(nl)
// Reads A16 (f16 ping), writes xcol (f32) and EITHER x16out (pong, layer 1)
// OR out2 (all_layers, layer 2).  grid (4, 64, 2), block 256.
__global__ __launch_bounds__(256)
void gemm_hw(const _Float16* __restrict__ A16base,
             const _Float16* __restrict__ W0, const _Float16* __restrict__ W1,
             const float* __restrict__ b0, const float* __restrict__ b1,
             float* __restrict__ xbase,
             _Float16* __restrict__ x16outbase,   // null on last layer
             float* __restrict__ out2base) {      // null on first layer
    const int lda = 512, ldb = 512, K = 512;
    __shared__ _Float16 As[64 * 32];    // 4 KB
    __shared__ _Float16 Bn[128 * 32];   // 8 KB
    __shared__ _Float16 Bg[128 * 32];   // 8 KB
    const int t    = threadIdx.x;
    const int wave = t >> 6;
    const int lane = t & 63;
    const int bm = blockIdx.y * 64;
    const int bn = blockIdx.x * 128;
    const int z  = blockIdx.z;
    const _Float16* A = A16base + (size_t)z * MOUT * 512;
    const _Float16* W = z ? W1 : W0;
    const float* bias = z ? b1 : b0;
    float* xcol = xbase + z * 512;
    _Float16* x16out = x16outbase ? x16outbase + (size_t)z * MOUT * 512 : nullptr;
    float* out2 = out2base ? out2base + z * 512 : nullptr;

    const int wm = (wave & 1) * 32;
    const int wn = (wave >> 1) * 64;

    const int rA = wave * 16 + (lane >> 2);
    const int rB = wave * 32 + (lane >> 2);
    const int kf = (lane & 3) * 8;

    const _Float16* Ag0 = A + (size_t)(bm + rA) * lda + kf;
    const _Float16* Bn0 = W + (size_t)(bn + rB) * ldb + kf;            // rows bn..
    const _Float16* Bn1 = Bn0 + (size_t)16 * ldb;
    const _Float16* Bg0 = W + (size_t)(512 + bn + rB) * ldb + kf;      // rows 512+bn..
    const _Float16* Bg1 = Bg0 + (size_t)16 * ldb;
    _Float16* As0  = &As[wave * 512];   // FIX: 512 f16 per inst (was 256)
    _Float16* Bns0 = &Bn[wave * 1024];
    _Float16* Bns1 = Bns0 + 512;
    _Float16* Bgs0 = &Bg[wave * 1024];
    _Float16* Bgs1 = Bgs0 + 512;

    const int fr = lane & 15;
    const int fq = (lane >> 4) * 8;

    floatx4 accn[2][4] = {};
    floatx4 accg[2][4] = {};

    for (int k0 = 0; k0 < K; k0 += 32) {
        GLD16(Ag0, As0);
        GLD16(Bn0, Bns0); GLD16(Bn1, Bns1);
        GLD16(Bg0, Bgs0); GLD16(Bg1, Bgs1);
        Ag0 += 32; Bn0 += 32; Bn1 += 32; Bg0 += 32; Bg1 += 32;
        __syncthreads();
        half8 af[2], bnf[4], bgf[4];
#pragma unroll
        for (int s = 0; s < 2; s++)
            af[s] = *(const half8*)&As[(wm + s * 16 + fr) * 32 + fq];
#pragma unroll
        for (int s = 0; s < 4; s++) {
            bnf[s] = *(const half8*)&Bn[(wn + s * 16 + fr) * 32 + fq];
            bgf[s] = *(const half8*)&Bg[(wn + s * 16 + fr) * 32 + fq];
        }
#pragma unroll
        for (int i = 0; i < 2; i++)
#pragma unroll
            for (int j = 0; j < 4; j++) {
                accn[i][j] = __builtin_amdgcn_mfma_f32_16x16x32_f16(
                    af[i], bnf[j], accn[i][j], 0, 0, 0);
                accg[i][j] = __builtin_amdgcn_mfma_f32_16x16x32_f16(
                    af[i], bgf[j], accg[i][j], 0, 0, 0);
            }
        __syncthreads();
    }

    const int rq = (lane >> 4) * 4;
    const int cc = lane & 15;
#pragma unroll
    for (int i = 0; i < 2; i++) {
        const int rbase = bm + wm + i * 16 + rq;
#pragma unroll
        for (int j = 0; j < 4; j++) {
            const int col = bn + wn + j * 16 + cc;
            const float bnl = bias[col];
            const float bgt = bias[512 + col];
#pragma unroll
            for (int r = 0; r < 4; r++) {
                const int row = rbase + r;
                const float nl = fmaxf(accn[i][j][r] + bnl, 0.f);
                const float g  = sigmoidf_(accg[i][j][r] + bgt);
                const float xo = xcol[(size_t)row * 1024 + col];
                const float v  = g * xo + (1.f - g) * nl;
                xcol[(size_t)row * 1024 + col] = v;
                if (out2)   out2[(size_t)row * 1024 + col] = v;
                if (x16out) x16out[(size_t)row * 512 + col] = (_Float16)v;
            }
        }
    }
}

// ---------------- windowed attention, dual-dir, f16 qkv ----------------
__global__ __launch_bounds__(256)
void attn_win(const _Float16* __restrict__ qkvall, _Float16* __restrict__ attall) {
    const int dir = blockIdx.y;
    const int dlo = dir ? 0 : -(WIDTH_ + 1);
    const _Float16* qkv = qkvall + (size_t)dir * MROWS * 1536;
    _Float16* att = attall + (size_t)dir * MROWS * 512;
    const int tid = blockIdx.x * 256 + threadIdx.x;
    const int h  = tid & 63;
    const int bi = tid >> 6;
    const int i  = bi % NSEQ;
    const int b  = bi / NSEQ;
    const int j0 = i + dlo;
    const float scale = 0.35355339059327373f;  // 1/sqrt(8)

    const half8 q8 = *(const half8*)(qkv + (size_t)bi * 1536 + h * 8);
    float q[8];
#pragma unroll
    for (int d = 0; d < 8; d++) q[d] = (float)q8[d];

    float s[18];
    float mx = -1e30f;
#pragma unroll
    for (int jj = 0; jj < 18; jj++) {
        const int j = j0 + jj;
        const int jc = j < 0 ? 0 : (j > NSEQ - 1 ? NSEQ - 1 : j);
        const half8 k8 = *(const half8*)(qkv + (size_t)(b * NSEQ + jc) * 1536 + 512 + h * 8);
        float d = 0.f;
#pragma unroll
        for (int dd = 0; dd < 8; dd++) d = fmaf(q[dd], (float)k8[dd], d);
        s[jj] = (j == jc) ? d * scale : -1e30f;
        mx = fmaxf(mx, s[jj]);
    }
    float sum = 0.f;
#pragma unroll
    for (int jj = 0; jj < 18; jj++) { s[jj] = __expf(s[jj] - mx); sum += s[jj]; }
    const float inv = 1.f / sum;

    float o[8] = {};
#pragma unroll
    for (int jj = 0; jj < 18; jj++) {
        const int j = j0 + jj;
        const int jc = j < 0 ? 0 : (j > NSEQ - 1 ? NSEQ - 1 : j);
        const half8 v8 = *(const half8*)(qkv + (size_t)(b * NSEQ + jc) * 1536 + 1024 + h * 8);
        const float p = s[jj];
#pragma unroll
        for (int dd = 0; dd < 8; dd++) o[dd] = fmaf(p, (float)v8[dd], o[dd]);
    }
    half8 o16;
#pragma unroll
    for (int d = 0; d < 8; d++) o16[d] = (_Float16)(o[d] * inv);
    *(half8*)&att[(size_t)bi * 512 + h * 8] = o16;
}

// ---------------- fused weight convert (all 6 tensors) ----------------
__global__ void cvt_all(const float* __restrict__ lq, const float* __restrict__ rq,
                        const float* __restrict__ lo, const float* __restrict__ ro,
                        const float* __restrict__ lh, const float* __restrict__ rh,
                        _Float16* __restrict__ dst) {
    int idx = blockIdx.x * blockDim.x + threadIdx.x;   // 1,048,576 float4s
    if (idx >= 1048576) return;
    const float* src; int off;
    if      (idx < 196608) { src = lq; off = idx; }
    else if (idx < 393216) { src = rq; off = idx - 196608; }
    else if (idx < 458752) { src = lo; off = idx - 393216; }
    else if (idx < 524288) { src = ro; off = idx - 458752; }
    else if (idx < 786432) { src = lh; off = idx - 524288; }
    else                   { src = rh; off = idx - 786432; }
    const float4 v = ((const float4*)src)[off];
    half4 h = { (_Float16)v.x, (_Float16)v.y, (_Float16)v.z, (_Float16)v.w };
    ((half4*)dst)[idx] = h;
}

// ---------------- pad concat -> f16 [MROWS,512] ----------------
__global__ void pad_concat16(const float* __restrict__ inp,
                             const float* __restrict__ lp,
                             const float* __restrict__ rp,
                             _Float16* __restrict__ out) {
    int idx = blockIdx.x * blockDim.x + threadIdx.x;   // MROWS*128
    if (idx >= MROWS * 128) return;
    const int c4 = idx & 127;
    const int t  = idx >> 7;
    const int n = t % NSEQ;
    const int b = t / NSEQ;
    const float* src;
    if (n < WIDTH_)            src = lp + n * 512;
    else if (n < WIDTH_ + S_)  src = inp + ((size_t)(b * S_ + n - WIDTH_)) * 512;
    else                       src = rp + (n - WIDTH_ - S_) * 512;
    const float4 v = *(const float4*)(src + c4 * 4);
    half4 h = { (_Float16)v.x, (_Float16)v.y, (_Float16)v.z, (_Float16)v.w };
    *(half4*)&out[(size_t)t * 512 + c4 * 4] = h;
}

extern "C" void kernel_launch(void* const* d_in, const int* in_sizes, int n_in,
                              void* d_out, int out_size, void* d_ws, size_t ws_size,
                              hipStream_t stream) {
    const float* inputs    = (const float*)d_in[0];
    const float* left_pad  = (const float*)d_in[1];
    const float* right_pad = (const float*)d_in[2];
    const float* l_Wqkv = (const float*)d_in[3];
    const float* l_bqkv = (const float*)d_in[4];
    const float* l_Wo   = (const float*)d_in[5];
    const float* l_bo   = (const float*)d_in[6];
    const float* r_Wqkv = (const float*)d_in[7];
    const float* r_bqkv = (const float*)d_in[8];
    const float* r_Wo   = (const float*)d_in[9];
    const float* r_bo   = (const float*)d_in[10];
    const float* lhw_W  = (const float*)d_in[11];
    const float* lhw_b  = (const float*)d_in[12];
    const float* rhw_W  = (const float*)d_in[13];
    const float* rhw_b  = (const float*)d_in[14];

    float* out = (float*)d_out;
    _Float16* h = (_Float16*)d_ws;

    // f16 arena offsets (f16 units)
    _Float16* padX16 = h;                    // 2,228,224
    _Float16* w16    = h + 2228224;          // 4,194,304
    _Float16* lqkv16 = w16;
    _Float16* rqkv16 = w16 + 786432;
    _Float16* lWo16  = w16 + 1572864;
    _Float16* rWo16  = w16 + 1835008;
    _Float16* lhw16  = w16 + 2097152;
    _Float16* rhw16  = w16 + 3145728;
    _Float16* qkv16  = h + 6422528;          // 13,369,344 (2 dirs)
    _Float16* att16  = h + 19791872;         // 4,456,448  (2 dirs)
    _Float16* x16a   = h + 24248320;         // 4,194,304  (2 dirs) ping
    _Float16* x16b   = h + 28442624;         // 4,194,304  (2 dirs) pong

    float* out_all  = out;            // all_layers [1,B,S,2D]
    float* out_last = out + OUTHALF;  // last       [B,S,2D]

    cvt_all<<<4096, 256, 0, stream>>>(l_Wqkv, r_Wqkv, l_Wo, r_Wo, lhw_W, rhw_W, w16);
    pad_concat16<<<(MROWS * 128 + 255) / 256, 256, 0, stream>>>(
        inputs, left_pad, right_pad, padX16);

    // QKV both dirs: [4352,512] x [1536,512]^T -> f16 [2][4352,1536]
    gemm_qkv<<<dim3(12, 34, 2), 256, 0, stream>>>(
        padX16, lqkv16, rqkv16, l_bqkv, r_bqkv, qkv16);

    // windowed attention both dirs -> att16 [2][4352,512]
    attn_win<<<dim3(MROWS * 64 / 256, 2), 256, 0, stream>>>(qkv16, att16);

    // Wo + slice: -> out_last cols (f32, ld 1024) + x16a (f16)
    gemm_wo<<<dim3(4, 68, 2), 256, 0, stream>>>(
        att16, lWo16, rWo16, l_bo, r_bo, out_last, x16a);

    // highway layer 1: reads x16a, writes xcol + x16b (no in-place race)
    gemm_hw<<<dim3(4, 64, 2), 256, 0, stream>>>(
        x16a, lhw16, rhw16, lhw_b, rhw_b, out_last, x16b, nullptr);
    // highway layer 2: reads x16b, writes xcol + out_all
    gemm_hw<<<dim3(4, 64, 2), 256, 0, stream>>>(
        x16b, lhw16 + 524288, rhw16 + 524288, lhw_b + 1024, rhw_b + 1024,
        out_last, nullptr, out_all);
}

// Round 5
// 220.558 us; speedup vs baseline: 3.7012x; 1.0385x over previous
//
#include <hip/hip_runtime.h>
#include <math.h>

#define B_ 8
#define S_ 512
#define D_ 512
#define WIDTH_ 16
#define NSEQ 544                 // S + 2*WIDTH
#define MROWS 4352               // B*NSEQ
#define MOUT 4096                // B*S
#define OUTHALF 4194304          // B*S*2D floats per output tensor

typedef _Float16 half8 __attribute__((ext_vector_type(8)));
typedef _Float16 half4 __attribute__((ext_vector_type(4)));
typedef float floatx4 __attribute__((ext_vector_type(4)));

// async global->LDS, 16B per lane, dest = wave-uniform base + lane*16
#define GLD16(g, l) __builtin_amdgcn_global_load_lds(                          \
    (const __attribute__((address_space(1))) void*)(g),                        \
    (__attribute__((address_space(3))) void*)(l), 16, 0, 0)

__device__ __forceinline__ float sigmoidf_(float x) {
    return 1.f / (1.f + __expf(-x));
}

// ================= QKV GEMM: 128x128 tile, f16 out, dual-dir =================
// C16[z][m,n] = sum_k A[m,k]*B[z][n,k] + bias[z][n]
// A: padX16 [4352,512] shared across z. grid (12, 34, 2), block 256.
__global__ __launch_bounds__(256)
void gemm_qkv(const _Float16* __restrict__ A,
              const _Float16* __restrict__ B0, const _Float16* __restrict__ B1,
              const float* __restrict__ bias0, const float* __restrict__ bias1,
              _Float16* __restrict__ C16) {
    const int lda = 512, ldb = 512, ldc = 1536, K = 512;
    __shared__ _Float16 As[128 * 32];
    __shared__ _Float16 Bs[128 * 32];
    const int t    = threadIdx.x;
    const int wave = t >> 6;
    const int lane = t & 63;
    const int bm = blockIdx.y * 128;
    const int bn = blockIdx.x * 128;
    const int z  = blockIdx.z;
    const _Float16* B = z ? B1 : B0;
    const float* bias = z ? bias1 : bias0;
    _Float16* C = C16 + (size_t)z * MROWS * 1536;
    const int wm = (wave & 1) * 64;
    const int wn = (wave >> 1) * 64;

    const int inst = wave * 2;
    const int r0 = inst * 16 + (lane >> 2);   // 16 rows per GLD16 inst
    const int kf = (lane & 3) * 8;

    const _Float16* Ag0 = A + (size_t)(bm + r0) * lda + kf;
    const _Float16* Ag1 = Ag0 + (size_t)16 * lda;
    const _Float16* Bg0 = B + (size_t)(bn + r0) * ldb + kf;
    const _Float16* Bg1 = Bg0 + (size_t)16 * ldb;
    _Float16* As0 = &As[inst * 512];          // 512 f16 per inst
    _Float16* As1 = As0 + 512;
    _Float16* Bs0 = &Bs[inst * 512];
    _Float16* Bs1 = Bs0 + 512;

    const int fr = lane & 15;
    const int fq = (lane >> 4) * 8;

    floatx4 acc[4][4] = {};

    for (int k0 = 0; k0 < K; k0 += 32) {
        GLD16(Ag0, As0); GLD16(Ag1, As1);
        GLD16(Bg0, Bs0); GLD16(Bg1, Bs1);
        Ag0 += 32; Ag1 += 32; Bg0 += 32; Bg1 += 32;
        __syncthreads();
        half8 af[4], bf[4];
#pragma unroll
        for (int s = 0; s < 4; s++) {
            af[s] = *(const half8*)&As[(wm + s * 16 + fr) * 32 + fq];
            bf[s] = *(const half8*)&Bs[(wn + s * 16 + fr) * 32 + fq];
        }
#pragma unroll
        for (int i = 0; i < 4; i++)
#pragma unroll
            for (int j = 0; j < 4; j++)
                acc[i][j] = __builtin_amdgcn_mfma_f32_16x16x32_f16(
                    af[i], bf[j], acc[i][j], 0, 0, 0);
        __syncthreads();
    }

    const int rq = (lane >> 4) * 4;
    const int cc = lane & 15;
#pragma unroll
    for (int i = 0; i < 4; i++) {
        const int rbase = bm + wm + i * 16 + rq;
#pragma unroll
        for (int j = 0; j < 4; j++) {
            const int col = bn + wn + j * 16 + cc;
            const float bv = bias[col];
#pragma unroll
            for (int r = 0; r < 4; r++)
                C[(size_t)(rbase + r) * ldc + col] = (_Float16)(acc[i][j][r] + bv);
        }
    }
}

// ======== Wo GEMM: 64x128 tile, dual-dir, fused slice epilogue ========
// attp[m,n] = sum_k att16[z][m,k]*Wo[z][n,k] + bo[z][n]; rows sliced
// [b,16:528] -> x16a f16 only (x carried in f16).  grid (4, 68, 2), block 256.
__global__ __launch_bounds__(256)
void gemm_wo(const _Float16* __restrict__ Aall,
             const _Float16* __restrict__ B0, const _Float16* __restrict__ B1,
             const float* __restrict__ bias0, const float* __restrict__ bias1,
             _Float16* __restrict__ x16base) { // +z*MOUT*512
    const int lda = 512, ldb = 512, K = 512;
    __shared__ _Float16 As[64 * 32];    // 4 KB
    __shared__ _Float16 Bs[128 * 32];   // 8 KB
    const int t    = threadIdx.x;
    const int wave = t >> 6;
    const int lane = t & 63;
    const int bm = blockIdx.y * 64;
    const int bn = blockIdx.x * 128;
    const int z  = blockIdx.z;
    const _Float16* A = Aall + (size_t)z * MROWS * 512;
    const _Float16* B = z ? B1 : B0;
    const float* bias = z ? bias1 : bias0;
    _Float16* x16 = x16base + (size_t)z * MOUT * 512;

    const int wm = (wave & 1) * 32;
    const int wn = (wave >> 1) * 64;

    const int rA = wave * 16 + (lane >> 2);        // A inst = wave (16 rows)
    const int rB = wave * 32 + (lane >> 2);        // B insts = 2w, 2w+1
    const int kf = (lane & 3) * 8;

    const _Float16* Ag0 = A + (size_t)(bm + rA) * lda + kf;
    const _Float16* Bg0 = B + (size_t)(bn + rB) * ldb + kf;
    const _Float16* Bg1 = Bg0 + (size_t)16 * ldb;
    _Float16* As0 = &As[wave * 512];
    _Float16* Bs0 = &Bs[wave * 1024];
    _Float16* Bs1 = Bs0 + 512;

    const int fr = lane & 15;
    const int fq = (lane >> 4) * 8;

    floatx4 acc[2][4] = {};

    for (int k0 = 0; k0 < K; k0 += 32) {
        GLD16(Ag0, As0);
        GLD16(Bg0, Bs0); GLD16(Bg1, Bs1);
        Ag0 += 32; Bg0 += 32; Bg1 += 32;
        __syncthreads();
        half8 af[2], bf[4];
#pragma unroll
        for (int s = 0; s < 2; s++)
            af[s] = *(const half8*)&As[(wm + s * 16 + fr) * 32 + fq];
#pragma unroll
        for (int s = 0; s < 4; s++)
            bf[s] = *(const half8*)&Bs[(wn + s * 16 + fr) * 32 + fq];
#pragma unroll
        for (int i = 0; i < 2; i++)
#pragma unroll
            for (int j = 0; j < 4; j++)
                acc[i][j] = __builtin_amdgcn_mfma_f32_16x16x32_f16(
                    af[i], bf[j], acc[i][j], 0, 0, 0);
        __syncthreads();
    }

    const int rq = (lane >> 4) * 4;
    const int cc = lane & 15;
#pragma unroll
    for (int i = 0; i < 2; i++) {
        const int rbase = bm + wm + i * 16 + rq;
#pragma unroll
        for (int r = 0; r < 4; r++) {
            const int row = rbase + r;
            const int b = row / NSEQ;
            const int s = row - b * NSEQ;
            if (s < WIDTH_ || s >= WIDTH_ + S_) continue;
            const int m = b * S_ + s - WIDTH_;
#pragma unroll
            for (int j = 0; j < 4; j++) {
                const int col = bn + wn + j * 16 + cc;
                x16[(size_t)m * 512 + col] = (_Float16)(acc[i][j][r] + bias[col]);
            }
        }
    }
}

// ==== Highway GEMM: 128x64 tile, dual-N (nonlin+gate), fused combine ====
// nl = x@Wnl^T + bnl; g = sigmoid(x@Wg^T + bg); x' = g*x + (1-g)*relu(nl)
// Reads x16in (f16); writes EITHER x16out (layer 1) OR out_last+out_all f32
// (layer 2).  grid (8, 32, 2), block 256.  Wave = 64 rows x 32 cols x {nl,g}:
// 8 ds_read_b128 per 16 MFMA (vs 10 in the old 64x128 layout).
__global__ __launch_bounds__(256)
void gemm_hw(const _Float16* __restrict__ x16inbase,
             const _Float16* __restrict__ W0, const _Float16* __restrict__ W1,
             const float* __restrict__ b0, const float* __restrict__ b1,
             _Float16* __restrict__ x16outbase,   // null on last layer
             float* __restrict__ outlastbase,     // last layer only
             float* __restrict__ outallbase) {    // last layer only
    const int lda = 512, ldb = 512, K = 512;
    __shared__ _Float16 As[128 * 32];   // 8 KB
    __shared__ _Float16 Bn[64 * 32];    // 4 KB
    __shared__ _Float16 Bg[64 * 32];    // 4 KB
    const int t    = threadIdx.x;
    const int wave = t >> 6;
    const int lane = t & 63;
    const int bm = blockIdx.y * 128;
    const int bn = blockIdx.x * 64;     // col block within [0,512)
    const int z  = blockIdx.z;
    const _Float16* A = x16inbase + (size_t)z * MOUT * 512;
    const _Float16* W = z ? W1 : W0;
    const float* bias = z ? b1 : b0;
    _Float16* x16out = x16outbase ? x16outbase + (size_t)z * MOUT * 512 : nullptr;

    const int wm = (wave & 1) * 64;
    const int wn = (wave >> 1) * 32;

    const int rA = wave * 32 + (lane >> 2);   // A insts = 2w, 2w+1 (32 rows/wave)
    const int rB = wave * 16 + (lane >> 2);   // Bn inst = w; Bg inst = w
    const int kf = (lane & 3) * 8;

    const _Float16* Ag0 = A + (size_t)(bm + rA) * lda + kf;
    const _Float16* Ag1 = Ag0 + (size_t)16 * lda;
    const _Float16* Bn0 = W + (size_t)(bn + rB) * ldb + kf;          // rows bn..
    const _Float16* Bg0 = W + (size_t)(512 + bn + rB) * ldb + kf;    // rows 512+bn..
    _Float16* As0  = &As[wave * 1024];
    _Float16* As1  = As0 + 512;
    _Float16* Bns0 = &Bn[wave * 512];
    _Float16* Bgs0 = &Bg[wave * 512];

    const int fr = lane & 15;
    const int fq = (lane >> 4) * 8;

    floatx4 accn[4][2] = {};
    floatx4 accg[4][2] = {};

    for (int k0 = 0; k0 < K; k0 += 32) {
        GLD16(Ag0, As0); GLD16(Ag1, As1);
        GLD16(Bn0, Bns0);
        GLD16(Bg0, Bgs0);
        Ag0 += 32; Ag1 += 32; Bn0 += 32; Bg0 += 32;
        __syncthreads();
        half8 af[4], bnf[2], bgf[2];
#pragma unroll
        for (int s = 0; s < 4; s++)
            af[s] = *(const half8*)&As[(wm + s * 16 + fr) * 32 + fq];
#pragma unroll
        for (int s = 0; s < 2; s++) {
            bnf[s] = *(const half8*)&Bn[(wn + s * 16 + fr) * 32 + fq];
            bgf[s] = *(const half8*)&Bg[(wn + s * 16 + fr) * 32 + fq];
        }
#pragma unroll
        for (int i = 0; i < 4; i++)
#pragma unroll
            for (int j = 0; j < 2; j++) {
                accn[i][j] = __builtin_amdgcn_mfma_f32_16x16x32_f16(
                    af[i], bnf[j], accn[i][j], 0, 0, 0);
                accg[i][j] = __builtin_amdgcn_mfma_f32_16x16x32_f16(
                    af[i], bgf[j], accg[i][j], 0, 0, 0);
            }
        __syncthreads();
    }

    float* outlast = outlastbase ? outlastbase + z * 512 : nullptr;
    float* outall  = outallbase  ? outallbase  + z * 512 : nullptr;

    const int rq = (lane >> 4) * 4;
    const int cc = lane & 15;
#pragma unroll
    for (int i = 0; i < 4; i++) {
        const int rbase = bm + wm + i * 16 + rq;
#pragma unroll
        for (int j = 0; j < 2; j++) {
            const int col = bn + wn + j * 16 + cc;
            const float bnl = bias[col];
            const float bgt = bias[512 + col];
#pragma unroll
            for (int r = 0; r < 4; r++) {
                const int row = rbase + r;
                const float nl = fmaxf(accn[i][j][r] + bnl, 0.f);
                const float g  = sigmoidf_(accg[i][j][r] + bgt);
                const float xo = (float)A[(size_t)row * 512 + col];
                const float v  = g * xo + (1.f - g) * nl;
                if (x16out) {
                    x16out[(size_t)row * 512 + col] = (_Float16)v;
                } else {
                    outlast[(size_t)row * 1024 + col] = v;
                    outall[(size_t)row * 1024 + col] = v;
                }
            }
        }
    }
}

// ---------------- windowed attention, dual-dir, f16 qkv ----------------
__global__ __launch_bounds__(256)
void attn_win(const _Float16* __restrict__ qkvall, _Float16* __restrict__ attall) {
    const int dir = blockIdx.y;
    const int dlo = dir ? 0 : -(WIDTH_ + 1);
    const _Float16* qkv = qkvall + (size_t)dir * MROWS * 1536;
    _Float16* att = attall + (size_t)dir * MROWS * 512;
    const int tid = blockIdx.x * 256 + threadIdx.x;
    const int h  = tid & 63;
    const int bi = tid >> 6;
    const int i  = bi % NSEQ;
    const int b  = bi / NSEQ;
    const int j0 = i + dlo;
    const float scale = 0.35355339059327373f;  // 1/sqrt(8)

    const half8 q8 = *(const half8*)(qkv + (size_t)bi * 1536 + h * 8);
    float q[8];
#pragma unroll
    for (int d = 0; d < 8; d++) q[d] = (float)q8[d];

    float s[18];
    float mx = -1e30f;
#pragma unroll
    for (int jj = 0; jj < 18; jj++) {
        const int j = j0 + jj;
        const int jc = j < 0 ? 0 : (j > NSEQ - 1 ? NSEQ - 1 : j);
        const half8 k8 = *(const half8*)(qkv + (size_t)(b * NSEQ + jc) * 1536 + 512 + h * 8);
        float d = 0.f;
#pragma unroll
        for (int dd = 0; dd < 8; dd++) d = fmaf(q[dd], (float)k8[dd], d);
        s[jj] = (j == jc) ? d * scale : -1e30f;
        mx = fmaxf(mx, s[jj]);
    }
    float sum = 0.f;
#pragma unroll
    for (int jj = 0; jj < 18; jj++) { s[jj] = __expf(s[jj] - mx); sum += s[jj]; }
    const float inv = 1.f / sum;

    float o[8] = {};
#pragma unroll
    for (int jj = 0; jj < 18; jj++) {
        const int j = j0 + jj;
        const int jc = j < 0 ? 0 : (j > NSEQ - 1 ? NSEQ - 1 : j);
        const half8 v8 = *(const half8*)(qkv + (size_t)(b * NSEQ + jc) * 1536 + 1024 + h * 8);
        const float p = s[jj];
#pragma unroll
        for (int dd = 0; dd < 8; dd++) o[dd] = fmaf(p, (float)v8[dd], o[dd]);
    }
    half8 o16;
#pragma unroll
    for (int d = 0; d < 8; d++) o16[d] = (_Float16)(o[d] * inv);
    *(half8*)&att[(size_t)bi * 512 + h * 8] = o16;
}

// ====== prep: fused weight convert (6 tensors) + pad-concat to f16 ======
// blocks [0, 4096): cvt (1,048,576 float4s); blocks [4096, 6272): pad-concat.
__global__ void prep(const float* __restrict__ lq, const float* __restrict__ rq,
                     const float* __restrict__ lo, const float* __restrict__ ro,
                     const float* __restrict__ lh, const float* __restrict__ rh,
                     _Float16* __restrict__ wdst,
                     const float* __restrict__ inp,
                     const float* __restrict__ lp,
                     const float* __restrict__ rp,
                     _Float16* __restrict__ padX) {
    const int gb = blockIdx.x;
    if (gb < 4096) {
        int idx = gb * 256 + threadIdx.x;
        const float* src; int off;
        if      (idx < 196608) { src = lq; off = idx; }
        else if (idx < 393216) { src = rq; off = idx - 196608; }
        else if (idx < 458752) { src = lo; off = idx - 393216; }
        else if (idx < 524288) { src = ro; off = idx - 458752; }
        else if (idx < 786432) { src = lh; off = idx - 524288; }
        else                   { src = rh; off = idx - 786432; }
        const float4 v = ((const float4*)src)[off];
        half4 h = { (_Float16)v.x, (_Float16)v.y, (_Float16)v.z, (_Float16)v.w };
        ((half4*)wdst)[idx] = h;
    } else {
        int idx = (gb - 4096) * 256 + threadIdx.x;   // MROWS*128 total
        const int c4 = idx & 127;
        const int t  = idx >> 7;
        const int n = t % NSEQ;
        const int b = t / NSEQ;
        const float* src;
        if (n < WIDTH_)            src = lp + n * 512;
        else if (n < WIDTH_ + S_)  src = inp + ((size_t)(b * S_ + n - WIDTH_)) * 512;
        else                       src = rp + (n - WIDTH_ - S_) * 512;
        const float4 v = *(const float4*)(src + c4 * 4);
        half4 h = { (_Float16)v.x, (_Float16)v.y, (_Float16)v.z, (_Float16)v.w };
        *(half4*)&padX[(size_t)t * 512 + c4 * 4] = h;
    }
}

extern "C" void kernel_launch(void* const* d_in, const int* in_sizes, int n_in,
                              void* d_out, int out_size, void* d_ws, size_t ws_size,
                              hipStream_t stream) {
    const float* inputs    = (const float*)d_in[0];
    const float* left_pad  = (const float*)d_in[1];
    const float* right_pad = (const float*)d_in[2];
    const float* l_Wqkv = (const float*)d_in[3];
    const float* l_bqkv = (const float*)d_in[4];
    const float* l_Wo   = (const float*)d_in[5];
    const float* l_bo   = (const float*)d_in[6];
    const float* r_Wqkv = (const float*)d_in[7];
    const float* r_bqkv = (const float*)d_in[8];
    const float* r_Wo   = (const float*)d_in[9];
    const float* r_bo   = (const float*)d_in[10];
    const float* lhw_W  = (const float*)d_in[11];
    const float* lhw_b  = (const float*)d_in[12];
    const float* rhw_W  = (const float*)d_in[13];
    const float* rhw_b  = (const float*)d_in[14];

    float* out = (float*)d_out;
    _Float16* h = (_Float16*)d_ws;

    // f16 arena offsets (f16 units)
    _Float16* padX16 = h;                    // 2,228,224
    _Float16* w16    = h + 2228224;          // 4,194,304
    _Float16* lqkv16 = w16;
    _Float16* rqkv16 = w16 + 786432;
    _Float16* lWo16  = w16 + 1572864;
    _Float16* rWo16  = w16 + 1835008;
    _Float16* lhw16  = w16 + 2097152;
    _Float16* rhw16  = w16 + 3145728;
    _Float16* qkv16  = h + 6422528;          // 13,369,344 (2 dirs)
    _Float16* att16  = h + 19791872;         // 4,456,448  (2 dirs)
    _Float16* x16a   = h + 24248320;         // 4,194,304  (2 dirs) ping
    _Float16* x16b   = h + 28442624;         // 4,194,304  (2 dirs) pong

    float* out_all  = out;            // all_layers [1,B,S,2D]
    float* out_last = out + OUTHALF;  // last       [B,S,2D]

    // fused weight cvt + pad concat
    prep<<<6272, 256, 0, stream>>>(l_Wqkv, r_Wqkv, l_Wo, r_Wo, lhw_W, rhw_W, w16,
                                   inputs, left_pad, right_pad, padX16);

    // QKV both dirs: [4352,512] x [1536,512]^T -> f16 [2][4352,1536]
    gemm_qkv<<<dim3(12, 34, 2), 256, 0, stream>>>(
        padX16, lqkv16, rqkv16, l_bqkv, r_bqkv, qkv16);

    // windowed attention both dirs -> att16 [2][4352,512]
    attn_win<<<dim3(MROWS * 64 / 256, 2), 256, 0, stream>>>(qkv16, att16);

    // Wo + slice -> x16a (f16)
    gemm_wo<<<dim3(4, 68, 2), 256, 0, stream>>>(
        att16, lWo16, rWo16, l_bo, r_bo, x16a);

    // highway layer 1: x16a -> x16b
    gemm_hw<<<dim3(8, 32, 2), 256, 0, stream>>>(
        x16a, lhw16, rhw16, lhw_b, rhw_b, x16b, nullptr, nullptr);
    // highway layer 2: x16b -> out_last + out_all (f32)
    gemm_hw<<<dim3(8, 32, 2), 256, 0, stream>>>(
        x16b, lhw16 + 524288, rhw16 + 524288, lhw_b + 1024, rhw_b + 1024,
        nullptr, out_last, out_all);
}